// Round 7
// baseline (254.732 us; speedup 1.0000x reference)
//
#include <hip/hip_runtime.h>

// Fused bilinear-2x-up -> leaky_relu(0.01) -> bilinear-0.5x-down
// == 3x3 clamped-edge stencil per output pixel:
//   up00 = .5625 e + .1875(b+d) + .0625 a   (etc. for the other 3 corners)
//   out  = 0.25 * sum(leaky_relu(up**))
//
// Ladder: R3 2x2 straight-line = 63 us; NT stores +21; 2x4 tile +19;
// XCD swizzles time-neutral; LDS-staged halo neutral (62.5). Counters:
// latency-bound (HBM 3-4 TB/s, VALU 30%, conflicts 0), and neither fetch
// bytes nor request count moved the needle -> the gap vs the ~43 us
// overlapped floor is UNHIDDEN LATENCY: each R3 wave loads, stalls,
// computes, dies -- no intra-wave overlap.
//
// R10: persistent threads, 4 tiles each, 2-deep register pipeline.
// Thread handles the same (py,px,c4) in images b0, b0+4k (k=0..3); the 20
// address offsets are b-invariant -> computed once (-30% VALU). Two named
// register sets alternate: loads of tile k+1 are issued before compute of
// tile k, so every wave keeps ~16 KB of reads in flight under its compute.
//
// Layout: (16,128,128,128) fp32 NHWC; C=128 -> 32 float4 groups, lane takes
// one c4 group: 32 consecutive lanes load 512 B contiguous per (row,col).

#define NEG_SLOPE 0.01f

__device__ __forceinline__ float lrelu(float v) {
    return fmaxf(v, NEG_SLOPE * v);  // slope < 1 => where(v>=0,v,s*v) == max
}

__device__ __forceinline__ float stencil(float a, float b, float c,
                                         float d, float e, float f,
                                         float g, float h, float i) {
    float up00 = 0.5625f * e + 0.1875f * (b + d) + 0.0625f * a;
    float up01 = 0.5625f * e + 0.1875f * (b + f) + 0.0625f * c;
    float up10 = 0.5625f * e + 0.1875f * (d + h) + 0.0625f * g;
    float up11 = 0.5625f * e + 0.1875f * (f + h) + 0.0625f * i;
    return 0.25f * (lrelu(up00) + lrelu(up01) + lrelu(up10) + lrelu(up11));
}

__device__ __forceinline__ float4 stencil4(const float4& a, const float4& b, const float4& c,
                                           const float4& d, const float4& e, const float4& f,
                                           const float4& g, const float4& h, const float4& i) {
    float4 o;
    o.x = stencil(a.x, b.x, c.x, d.x, e.x, f.x, g.x, h.x, i.x);
    o.y = stencil(a.y, b.y, c.y, d.y, e.y, f.y, g.y, h.y, i.y);
    o.z = stencil(a.z, b.z, c.z, d.z, e.z, f.z, g.z, h.z, i.z);
    o.w = stencil(a.w, b.w, c.w, d.w, e.w, f.w, g.w, h.w, i.w);
    return o;
}

// 16 named loads from base pointer P (float4 units), offsets oRC.
#define LOAD_SET(S, P)                                                        \
    const float4 S##00 = (P)[o00], S##01 = (P)[o01], S##02 = (P)[o02],        \
                 S##03 = (P)[o03],                                            \
                 S##10 = (P)[o10], S##11 = (P)[o11], S##12 = (P)[o12],        \
                 S##13 = (P)[o13],                                            \
                 S##20 = (P)[o20], S##21 = (P)[o21], S##22 = (P)[o22],        \
                 S##23 = (P)[o23],                                            \
                 S##30 = (P)[o30], S##31 = (P)[o31], S##32 = (P)[o32],        \
                 S##33 = (P)[o33];

#define CSTORE_SET(S, Q)                                                      \
    (Q)[s00] = stencil4(S##00, S##01, S##02, S##10, S##11, S##12,             \
                        S##20, S##21, S##22);                                 \
    (Q)[s01] = stencil4(S##01, S##02, S##03, S##11, S##12, S##13,             \
                        S##21, S##22, S##23);                                 \
    (Q)[s10] = stencil4(S##10, S##11, S##12, S##20, S##21, S##22,             \
                        S##30, S##31, S##32);                                 \
    (Q)[s11] = stencil4(S##11, S##12, S##13, S##21, S##22, S##23,             \
                        S##31, S##32, S##33);

__global__ __launch_bounds__(256) void ActivationFilter_kernel(
        const float4* __restrict__ in, float4* __restrict__ out) {
    // thread -> (b0, py, px, c4): 4 * 64 * 64 * 32 = 524,288 threads;
    // each handles images b0 + {0,4,8,12}. Same bit layout as the 63us R3
    // kernel (blk%8 = px_hi -> per-XCD vertical strip, py sequential).
    const int t  = blockIdx.x * 256 + threadIdx.x;
    const int c4 = t & 31;
    const int px = (t >> 5) & 63;
    const int py = (t >> 11) & 63;
    const int b0 = t >> 17;                   // 0..3

    const int x0 = px << 1, y0 = py << 1;
    const int xm = max(x0 - 1, 0), x3 = min(x0 + 2, 127);
    const int ym = max(y0 - 1, 0), y3 = min(y0 + 2, 127);

    // Per-image float4-unit offsets (b-invariant), computed once.
#define IOFF(Y, X) (((((Y) << 7) + (X)) << 5) + c4)
    const int o00 = IOFF(ym, xm),   o01 = IOFF(ym, x0),
              o02 = IOFF(ym, x0+1), o03 = IOFF(ym, x3);
    const int o10 = IOFF(y0, xm),   o11 = IOFF(y0, x0),
              o12 = IOFF(y0, x0+1), o13 = IOFF(y0, x3);
    const int o20 = IOFF(y0+1, xm),   o21 = IOFF(y0+1, x0),
              o22 = IOFF(y0+1, x0+1), o23 = IOFF(y0+1, x3);
    const int o30 = IOFF(y3, xm),   o31 = IOFF(y3, x0),
              o32 = IOFF(y3, x0+1), o33 = IOFF(y3, x3);
    const int s00 = IOFF(y0, x0),   s01 = IOFF(y0, x0+1);
    const int s10 = IOFF(y0+1, x0), s11 = IOFF(y0+1, x0+1);
#undef IOFF

    const int IMG  = 128 * 128 * 32;          // float4 units per image
    const int IMG4 = IMG << 2;                // stride of 4 images

    const float4* p0 = in  + b0 * IMG;
    float4*       q0 = out + b0 * IMG;
    const float4* p1 = p0 + IMG4;
    float4*       q1 = q0 + IMG4;
    const float4* p2 = p1 + IMG4;
    float4*       q2 = q1 + IMG4;
    const float4* p3 = p2 + IMG4;
    float4*       q3 = q2 + IMG4;

    // 2-deep pipeline: loads of tile k+1 issue before compute of tile k.
    LOAD_SET(A, p0)
    LOAD_SET(B, p1)
    CSTORE_SET(A, q0)
    LOAD_SET(C, p2)
    CSTORE_SET(B, q1)
    LOAD_SET(D, p3)
    CSTORE_SET(C, q2)
    CSTORE_SET(D, q3)
}

extern "C" void kernel_launch(void* const* d_in, const int* in_sizes, int n_in,
                              void* d_out, int out_size, void* d_ws, size_t ws_size,
                              hipStream_t stream) {
    const float4* in = (const float4*)d_in[0];
    float4* out = (float4*)d_out;
    // 524,288 threads -> 2048 blocks of 256
    ActivationFilter_kernel<<<dim3(2048), dim3(256), 0, stream>>>(in, out);
}

// Round 8
// 223.060 us; speedup vs baseline: 1.1420x; 1.1420x over previous
//
#include <hip/hip_runtime.h>

// Fused bilinear-2x-up -> leaky_relu(0.01) -> bilinear-0.5x-down
// == 3x3 clamped-edge stencil per output pixel:
//   up00 = .5625 e + .1875(b+d) + .0625 a   (etc. for the other 3 corners)
//   out  = 0.25 * sum(leaky_relu(up**))
//
// Ladder: R3 2x2 straight-line = 63 us; NT stores +21; 2x4 tile +19;
// XCD swizzles time-neutral; LDS halo neutral; 4-image reg pipeline +39
// (VGPR 148 -> 3 waves/SIMD, 2048 blocks -> no churn).
//
// R11 diagnosis from the counter arithmetic: VALUBusy 30% -> ~1400 VALU cyc
// per wave vs ~3300 cyc memory stall; 16 independent loads should stall
// once (~800 cy) -- but VGPR_Count=48 proves the compiler batched the
// loads ~4 deep (16 float4 results alone need 64 VGPRs), re-stalling 4x
// per wave. The limiter is per-wave MLP destroyed by VGPR-minimizing
// scheduling, not bytes/requests/locality (all falsified by R4-R10).
//
// Fix: sched_barrier(0) between the 16 loads and the compute -- nothing
// crosses, so all 16 results are live at once: back-to-back issue, one
// vmcnt drain. Costs VGPR (~90, 5-6 waves/SIMD) -- per-SIMD outstanding
// loads still rise ~32 -> ~90.
//
// Layout: (16,128,128,128) fp32 NHWC; C=128 -> 32 float4 groups, lane takes
// one c4 group: 32 consecutive lanes load 512 B contiguous per (row,col).

#define NEG_SLOPE 0.01f

__device__ __forceinline__ float lrelu(float v) {
    return fmaxf(v, NEG_SLOPE * v);  // slope < 1 => where(v>=0,v,s*v) == max
}

__device__ __forceinline__ float stencil(float a, float b, float c,
                                         float d, float e, float f,
                                         float g, float h, float i) {
    float up00 = 0.5625f * e + 0.1875f * (b + d) + 0.0625f * a;
    float up01 = 0.5625f * e + 0.1875f * (b + f) + 0.0625f * c;
    float up10 = 0.5625f * e + 0.1875f * (d + h) + 0.0625f * g;
    float up11 = 0.5625f * e + 0.1875f * (f + h) + 0.0625f * i;
    return 0.25f * (lrelu(up00) + lrelu(up01) + lrelu(up10) + lrelu(up11));
}

__device__ __forceinline__ float4 stencil4(const float4& a, const float4& b, const float4& c,
                                           const float4& d, const float4& e, const float4& f,
                                           const float4& g, const float4& h, const float4& i) {
    float4 o;
    o.x = stencil(a.x, b.x, c.x, d.x, e.x, f.x, g.x, h.x, i.x);
    o.y = stencil(a.y, b.y, c.y, d.y, e.y, f.y, g.y, h.y, i.y);
    o.z = stencil(a.z, b.z, c.z, d.z, e.z, f.z, g.z, h.z, i.z);
    o.w = stencil(a.w, b.w, c.w, d.w, e.w, f.w, g.w, h.w, i.w);
    return o;
}

__global__ __launch_bounds__(256) void ActivationFilter_kernel(
        const float4* __restrict__ in, float4* __restrict__ out) {
    // thread -> (b, y-pair, x-pair, c4): 16 * 64 * 64 * 32 = 2,097,152
    const int t  = blockIdx.x * 256 + threadIdx.x;
    const int c4 = t & 31;
    const int px = (t >> 5) & 63;
    const int py = (t >> 11) & 63;
    const int b  = t >> 17;

    const int x0 = px << 1, y0 = py << 1;
    const int xm = max(x0 - 1, 0), x3 = min(x0 + 2, 127);
    const int ym = max(y0 - 1, 0), y3 = min(y0 + 2, 127);

    const int rb = b << 7;  // b*128
    // float4-unit address of (b, Y, X, c4)
#define ADDR(Y, X) (((((rb + (Y)) << 7) + (X)) << 5) + c4)

    // 4x4 clamped neighborhood: rows {ym, y0, y0+1, y3} x cols {xm, x0, x0+1, x3}
    const float4 v00 = in[ADDR(ym,   xm)], v01 = in[ADDR(ym,   x0)],
                 v02 = in[ADDR(ym,   x0+1)], v03 = in[ADDR(ym,   x3)];
    const float4 v10 = in[ADDR(y0,   xm)], v11 = in[ADDR(y0,   x0)],
                 v12 = in[ADDR(y0,   x0+1)], v13 = in[ADDR(y0,   x3)];
    const float4 v20 = in[ADDR(y0+1, xm)], v21 = in[ADDR(y0+1, x0)],
                 v22 = in[ADDR(y0+1, x0+1)], v23 = in[ADDR(y0+1, x3)];
    const float4 v30 = in[ADDR(y3,   xm)], v31 = in[ADDR(y3,   x0)],
                 v32 = in[ADDR(y3,   x0+1)], v33 = in[ADDR(y3,   x3)];

    // MLP fence: nothing crosses -> all 16 loads issue before any consume,
    // forcing one back-to-back load burst per wave instead of ~4-deep
    // VGPR-saving batches.
    __builtin_amdgcn_sched_barrier(0);

    out[ADDR(y0,   x0  )] = stencil4(v00, v01, v02, v10, v11, v12, v20, v21, v22);
    out[ADDR(y0,   x0+1)] = stencil4(v01, v02, v03, v11, v12, v13, v21, v22, v23);
    out[ADDR(y0+1, x0  )] = stencil4(v10, v11, v12, v20, v21, v22, v30, v31, v32);
    out[ADDR(y0+1, x0+1)] = stencil4(v11, v12, v13, v21, v22, v23, v31, v32, v33);
#undef ADDR
}

extern "C" void kernel_launch(void* const* d_in, const int* in_sizes, int n_in,
                              void* d_out, int out_size, void* d_ws, size_t ws_size,
                              hipStream_t stream) {
    const float4* in = (const float4*)d_in[0];
    float4* out = (float4*)d_out;
    // 2,097,152 threads -> 8192 blocks of 256
    ActivationFilter_kernel<<<dim3(8192), dim3(256), 0, stream>>>(in, out);
}